// Round 6
// baseline (283.657 us; speedup 1.0000x reference)
//
#include <hip/hip_runtime.h>
#include <hip/hip_bf16.h>

// ConvEGNN3 round 6: round-4 structure (140us proven) + register diet for
// 3 waves/SIMD. a2/a3 weight fragments live in LDS (staged once, shared by
// all 4 waves, re-read per iter as transients), w1l/wx2 in LDS. Live regs
// ~150 under the (256,3) cap of 170 (round-3's spill was live 200 > 170).

typedef __attribute__((ext_vector_type(8))) short short8;
typedef __attribute__((ext_vector_type(4))) float f32x4;
typedef __attribute__((ext_vector_type(2))) float f32x2;
typedef __attribute__((ext_vector_type(2))) unsigned int u32x2;
typedef __attribute__((ext_vector_type(4))) unsigned int u32x4;

#define NODES 16384
#define NPB   16
#define NBLK  (NODES / NPB)

#define MFMA16(a, b, c) __builtin_amdgcn_mfma_f32_16x16x32_bf16((a), (b), (c), 0, 0, 0)

__device__ __forceinline__ unsigned short f2bf(float f) {
  unsigned int u = __float_as_uint(f);
  u += 0x7FFFu + ((u >> 16) & 1u);
  return (unsigned short)(u >> 16);
}
__device__ __forceinline__ unsigned int pk2(float lo, float hi) {
  unsigned int a = __float_as_uint(hi) + 0x8000u;
  unsigned int b = __float_as_uint(lo) + 0x8000u;
  return __builtin_amdgcn_perm(a, b, 0x07060302u);
}
__device__ __forceinline__ float bfl(unsigned int u) { return __uint_as_float(u << 16); }
__device__ __forceinline__ float bfh(unsigned int u) { return __uint_as_float(u & 0xFFFF0000u); }
__device__ __forceinline__ float silu_f(float x) {
  return x * __builtin_amdgcn_rcpf(1.f + __expf(-x));
}
__device__ __forceinline__ f32x4 silu4(f32x4 x) {
  f32x4 r; r[0]=silu_f(x[0]); r[1]=silu_f(x[1]); r[2]=silu_f(x[2]); r[3]=silu_f(x[3]); return r;
}
__device__ __forceinline__ short8 packb(f32x4 a, f32x4 b) {
  u32x4 t;
  t[0] = pk2(a[0], a[1]); t[1] = pk2(a[2], a[3]);
  t[2] = pk2(b[0], b[1]); t[3] = pk2(b[2], b[3]);
  return __builtin_bit_cast(short8, t);
}
__device__ __forceinline__ short8 ldfragT(const float* __restrict__ W, int k0, int col) {
  short8 r;
  #pragma unroll
  for (int m = 0; m < 8; m++) r[m] = (short)f2bf(W[(k0 + m) * 64 + col]);
  return r;
}

__global__ __launch_bounds__(256, 3) void egnn_mfma(
    const float* __restrict__ ped, const float* __restrict__ h_st,
    const float* __restrict__ h_neigh, const float* __restrict__ rela,
    const unsigned char* __restrict__ mask8,
    const float* __restrict__ We1, const float* __restrict__ be1,
    const float* __restrict__ We2, const float* __restrict__ be2,
    const float* __restrict__ Wx1, const float* __restrict__ bx1,
    const float* __restrict__ Wx2, const float* __restrict__ bx2,
    const float* __restrict__ Wh1, const float* __restrict__ bh1,
    const float* __restrict__ Wh2, const float* __restrict__ bh2,
    float* __restrict__ out)
{
  __shared__ __align__(16) float s_hst[16][64];
  __shared__ __align__(16) float s_u[16][64];
  __shared__ __align__(16) float s_miw[4][16][64];
  __shared__ __align__(16) unsigned int s_scr[4][16][36];
  __shared__ __align__(16) short8 s_af[16][64];   // c = 8*g + 2*mt + kk; g0=We2, g1=Wx1
  __shared__ float s_cvec[2][64];   // be2, bx1
  __shared__ float s_w1l[64];       // We1 dist row
  __shared__ float s_wx2[64];       // Wx2
  __shared__ float s_aggx[4][16], s_aggy[4][16], s_nn[4][16];
  __shared__ int s_flags[2];

  const int t  = threadIdx.x;
  const int l  = t & 63;
  const int w  = t >> 6;
  const int lg = l >> 4;
  const int jl = l & 15;
  const int base = blockIdx.x * NPB;

  if (t == 0) { s_flags[0] = 1; s_flags[1] = 1; }
  __syncthreads();
  {
    const unsigned int* mw = (const unsigned int*)mask8;
    unsigned int iok = 1, fok = 1;
    #pragma unroll
    for (int q = 0; q < 4; q++) {
      unsigned int v = mw[t * 4 + q];
      if (v > 1u) iok = 0;
      if (v != 0u && v != 0x3F800000u) fok = 0;
    }
    if (!iok) atomicAnd(&s_flags[0], 0);
    if (!fok) atomicAnd(&s_flags[1], 0);
  }
  {
    const f32x4* src = (const f32x4*)(h_st + (size_t)base * 64);
    f32x4* dst = (f32x4*)&s_hst[0][0];
    dst[t] = src[t];
    if (t < 64)        s_cvec[0][t] = be2[t];
    else if (t < 128)  s_cvec[1][t - 64] = bx1[t - 64];
    else if (t < 192)  s_w1l[t - 128] = We1[128 * 64 + (t - 128)];
    else               s_wx2[t - 192] = Wx2[t - 192];
  }
  // stage a2/a3 fragments into LDS: wave w stages combos 4w..4w+3
  #pragma unroll
  for (int ci = 0; ci < 4; ci++) {
    const int c  = 4 * w + ci;
    const int g  = c >> 3, mt = (c >> 1) & 3, kk = c & 1;
    const float* W = g ? Wx1 : We2;
    s_af[c][l] = ldfragT(W, 8 * lg + 32 * kk, 16 * mt + jl);
  }
  __syncthreads();
  const int mode = s_flags[0] ? 0 : (s_flags[1] ? 1 : 2);

  auto ldmask = [&](size_t idx) -> float {
    if (mode == 0)      return (((const int*)mask8)[idx] != 0) ? 1.f : 0.f;
    else if (mode == 1) return (((const float*)mask8)[idx] != 0.f) ? 1.f : 0.f;
    else                return (mask8[idx] != 0) ? 1.f : 0.f;
  };

  // ---- U = be1 + h_st @ We1[0:64] ----
  {
    f32x4 uacc = {0.f, 0.f, 0.f, 0.f};
    #pragma unroll
    for (int kk = 0; kk < 2; kk++) {
      short8 au = ldfragT(We1, 8 * lg + 32 * kk, 16 * w + jl);
      f32x4 q0 = *(const f32x4*)&s_hst[jl][8 * lg + 32 * kk];
      f32x4 q1 = *(const f32x4*)&s_hst[jl][8 * lg + 32 * kk + 4];
      uacc = MFMA16(au, packb(q0, q1), uacc);
    }
    f32x4 b1v = *(const f32x4*)(be1 + 16 * w + 4 * lg);
    *(f32x4*)&s_u[jl][16 * w + 4 * lg] = uacc + b1v;
  }

  // ---- a1 (We1 lower) fragments stay in registers (used first) ----
  short8 a1[4][2];
  #pragma unroll
  for (int mt = 0; mt < 4; mt++)
    #pragma unroll
    for (int kk = 0; kk < 2; kk++)
      a1[mt][kk] = ldfragT(We1 + 64 * 64, 8 * lg + 32 * kk, 16 * mt + jl);
  const float bx2s = bx2[0];

  // ---- initial prefetch (node 0) ----
  const float* hn_lane = h_neigh + ((size_t)base * 64 + 16 * w + jl) * 64 + 8 * lg;
  const size_t ro = (size_t)base * 64 + 16 * w + jl;
  f32x4 pf0 = *(const f32x4*)(hn_lane + 0);
  f32x4 pf1 = *(const f32x4*)(hn_lane + 4);
  f32x4 pf2 = *(const f32x4*)(hn_lane + 32);
  f32x4 pf3 = *(const f32x4*)(hn_lane + 36);
  f32x2 pre = *(const f32x2*)(rela + ro * 6);
  float pmf = ldmask(ro);
  __syncthreads();  // s_u + s_af ready

  // =========================== main loop ===========================
  #pragma unroll 1
  for (int nl = 0; nl < NPB; nl++) {
    f32x4 c0 = pf0, c1 = pf1, c2 = pf2, c3 = pf3;
    f32x2 rr = pre; float mf = pmf;
    if (nl < NPB - 1) {
      const float* p = hn_lane + (size_t)(nl + 1) * 4096;
      pf0 = *(const f32x4*)(p + 0);  pf1 = *(const f32x4*)(p + 4);
      pf2 = *(const f32x4*)(p + 32); pf3 = *(const f32x4*)(p + 36);
      pre = *(const f32x2*)(rela + (ro + (size_t)(nl + 1) * 64) * 6);
      pmf = ldmask(ro + (size_t)(nl + 1) * 64);
    }
    const short8 b1k0 = packb(c0, c1);
    const short8 b1k1 = packb(c2, c3);
    const float d = sqrtf(rr[0] * rr[0] + rr[1] * rr[1]);

    float msum = mf;
    msum += __shfl_xor(msum, 1, 64); msum += __shfl_xor(msum, 2, 64);
    msum += __shfl_xor(msum, 4, 64); msum += __shfl_xor(msum, 8, 64);
    if (l == 0) s_nn[w][nl] = msum;

    // ---- GEMM1: E^T ----
    f32x4 acc[4];
    #pragma unroll
    for (int ht = 0; ht < 4; ht++) {
      const f32x4 wl = *(const f32x4*)&s_w1l[16 * ht + 4 * lg];
      acc[ht] = *(const f32x4*)&s_u[nl][16 * ht + 4 * lg] + d * wl;
      acc[ht] = MFMA16(a1[ht][0], b1k0, acc[ht]);
      acc[ht] = MFMA16(a1[ht][1], b1k1, acc[ht]);
    }
    #pragma unroll
    for (int ht = 0; ht < 4; ht++) {
      f32x4 e = silu4(acc[ht]);
      u32x2 wv; wv[0] = pk2(e[0], e[1]); wv[1] = pk2(e[2], e[3]);
      *(u32x2*)&s_scr[w][jl][8 * ht + 2 * lg] = wv;
    }
    // fetch a2 fragments from LDS (overlaps scratch write->read latency)
    short8 f2[4][2];
    #pragma unroll
    for (int mt = 0; mt < 4; mt++)
      #pragma unroll
      for (int kk = 0; kk < 2; kk++)
        f2[mt][kk] = s_af[2 * mt + kk][l];
    short8 b2k0 = *(const short8*)&s_scr[w][jl][4 * lg];
    short8 b2k1 = *(const short8*)&s_scr[w][jl][16 + 4 * lg];

    // ---- GEMM2: M^T ----
    #pragma unroll
    for (int ht = 0; ht < 4; ht++) {
      acc[ht] = *(const f32x4*)&s_cvec[0][16 * ht + 4 * lg];
      acc[ht] = MFMA16(f2[ht][0], b2k0, acc[ht]);
      acc[ht] = MFMA16(f2[ht][1], b2k1, acc[ht]);
    }
    #pragma unroll
    for (int ht = 0; ht < 4; ht++) {
      f32x4 m = silu4(acc[ht]) * mf;
      u32x2 wv; wv[0] = pk2(m[0], m[1]); wv[1] = pk2(m[2], m[3]);
      *(u32x2*)&s_scr[w][jl][8 * ht + 2 * lg] = wv;
    }
    // fetch a3 fragments from LDS
    short8 f3[4][2];
    #pragma unroll
    for (int mt = 0; mt < 4; mt++)
      #pragma unroll
      for (int kk = 0; kk < 2; kk++)
        f3[mt][kk] = s_af[8 + 2 * mt + kk][l];
    short8 b3k0 = *(const short8*)&s_scr[w][jl][4 * lg];
    short8 b3k1 = *(const short8*)&s_scr[w][jl][16 + 4 * lg];

    // m_i partial
    {
      const int hw = l & 31, jh = l >> 5;
      float pe = 0.f, po = 0.f;
      #pragma unroll
      for (int c = 0; c < 8; c++) {
        unsigned int v = s_scr[w][8 * jh + c][hw];
        pe += bfl(v); po += bfh(v);
      }
      pe += __shfl_xor(pe, 32, 64);
      po += __shfl_xor(po, 32, 64);
      if (l < 32) {
        f32x2 v2; v2[0] = pe; v2[1] = po;
        *(f32x2*)&s_miw[w][nl][2 * hw] = v2;
      }
    }

    // ---- GEMM3: G^T + gate ----
    #pragma unroll
    for (int ht = 0; ht < 4; ht++) {
      acc[ht] = *(const f32x4*)&s_cvec[1][16 * ht + 4 * lg];
      acc[ht] = MFMA16(f3[ht][0], b3k0, acc[ht]);
      acc[ht] = MFMA16(f3[ht][1], b3k1, acc[ht]);
    }
    float gg = 0.f;
    #pragma unroll
    for (int ht = 0; ht < 4; ht++) {
      const f32x4 wx = *(const f32x4*)&s_wx2[16 * ht + 4 * lg];
      f32x4 g = silu4(acc[ht]);
      gg += g[0] * wx[0] + g[1] * wx[1] + g[2] * wx[2] + g[3] * wx[3];
    }
    gg += __shfl_xor(gg, 16, 64);
    gg += __shfl_xor(gg, 32, 64);
    const float gate = gg + bx2s;

    float ax = rr[0] * gate, ay = rr[1] * gate;
    ax += __shfl_xor(ax, 1, 64); ay += __shfl_xor(ay, 1, 64);
    ax += __shfl_xor(ax, 2, 64); ay += __shfl_xor(ay, 2, 64);
    ax += __shfl_xor(ax, 4, 64); ay += __shfl_xor(ay, 4, 64);
    ax += __shfl_xor(ax, 8, 64); ay += __shfl_xor(ay, 8, 64);
    if (l == 0) { s_aggx[w][nl] = ax; s_aggy[w][nl] = ay; }
  }
  __syncthreads();

  // ---- x_new ----
  if (t < 32) {
    const int node = t >> 1, c = t & 1;
    const float nn = s_nn[0][node] + s_nn[1][node] + s_nn[2][node] + s_nn[3][node];
    const float ag = (c ? (s_aggy[0][node] + s_aggy[1][node] + s_aggy[2][node] + s_aggy[3][node])
                        : (s_aggx[0][node] + s_aggx[1][node] + s_aggx[2][node] + s_aggx[3][node]));
    out[(size_t)(base + node) * 2 + c] =
        ped[(size_t)(base + node) * 2 + c] + ag / (nn + 1e-6f);
  }

  // ---- f_h batched over 16 nodes ----
  {
    f32x4 hacc = *(const f32x4*)(bh1 + 16 * w + 4 * lg);
    #pragma unroll
    for (int kk = 0; kk < 4; kk++) {
      short8 ah = ldfragT(Wh1, 8 * lg + 32 * kk, 16 * w + jl);
      f32x4 q0, q1;
      if (kk < 2) {
        q0 = *(const f32x4*)&s_hst[jl][8 * lg + 32 * kk];
        q1 = *(const f32x4*)&s_hst[jl][8 * lg + 32 * kk + 4];
      } else {
        const int off = 8 * lg + 32 * (kk - 2);
        q0 = *(const f32x4*)&s_miw[0][jl][off]     + *(const f32x4*)&s_miw[1][jl][off]
           + *(const f32x4*)&s_miw[2][jl][off]     + *(const f32x4*)&s_miw[3][jl][off];
        q1 = *(const f32x4*)&s_miw[0][jl][off + 4] + *(const f32x4*)&s_miw[1][jl][off + 4]
           + *(const f32x4*)&s_miw[2][jl][off + 4] + *(const f32x4*)&s_miw[3][jl][off + 4];
      }
      hacc = MFMA16(ah, packb(q0, q1), hacc);
    }
    f32x4 h1 = silu4(hacc);
    u32x2 wv; wv[0] = pk2(h1[0], h1[1]); wv[1] = pk2(h1[2], h1[3]);
    *(u32x2*)&s_scr[0][jl][8 * w + 2 * lg] = wv;
  }
  __syncthreads();
  {
    short8 hb0 = *(const short8*)&s_scr[0][jl][4 * lg];
    short8 hb1 = *(const short8*)&s_scr[0][jl][16 + 4 * lg];
    short8 aw0 = ldfragT(Wh2, 8 * lg,      16 * w + jl);
    short8 aw1 = ldfragT(Wh2, 8 * lg + 32, 16 * w + jl);
    f32x4 oacc = *(const f32x4*)(bh2 + 16 * w + 4 * lg);
    oacc = MFMA16(aw0, hb0, oacc);
    oacc = MFMA16(aw1, hb1, oacc);
    f32x4 res = oacc + *(const f32x4*)&s_hst[jl][16 * w + 4 * lg];
    *(f32x4*)(out + 32768 + (size_t)(base + jl) * 64 + 16 * w + 4 * lg) = res;
  }
}

extern "C" void kernel_launch(void* const* d_in, const int* in_sizes, int n_in,
                              void* d_out, int out_size, void* d_ws, size_t ws_size,
                              hipStream_t stream) {
  (void)in_sizes; (void)n_in; (void)out_size; (void)d_ws; (void)ws_size;
  const float* ped     = (const float*)d_in[0];
  const float* h_st    = (const float*)d_in[1];
  const float* h_neigh = (const float*)d_in[2];
  const float* rela    = (const float*)d_in[3];
  const unsigned char* mask = (const unsigned char*)d_in[4];
  const float* We1 = (const float*)d_in[5];  const float* be1 = (const float*)d_in[6];
  const float* We2 = (const float*)d_in[7];  const float* be2 = (const float*)d_in[8];
  const float* Wx1 = (const float*)d_in[9];  const float* bx1 = (const float*)d_in[10];
  const float* Wx2 = (const float*)d_in[11]; const float* bx2 = (const float*)d_in[12];
  const float* Wh1 = (const float*)d_in[13]; const float* bh1 = (const float*)d_in[14];
  const float* Wh2 = (const float*)d_in[15]; const float* bh2 = (const float*)d_in[16];

  hipLaunchKernelGGL(egnn_mfma, dim3(NBLK), dim3(256), 0, stream,
                     ped, h_st, h_neigh, rela, mask,
                     We1, be1, We2, be2, Wx1, bx1, Wx2, bx2,
                     Wh1, bh1, Wh2, bh2, (float*)d_out);
}

// Round 7
// 208.628 us; speedup vs baseline: 1.3596x; 1.3596x over previous
//
#include <hip/hip_runtime.h>
#include <hip/hip_bf16.h>

// ConvEGNN3 round 7: round-5 dual-node phase-paired structure, register-fixed.
// Law learned (r3+r6): __launch_bounds__(256,N) => total V+A budget 512/N,
// split ~evenly; (256,3) caps VGPR at 84 -> spill. Stay at (256,2).
// Round-5 spilled (~240 live) because prefetch COPIES (cA*=pA*) coexisted
// with the next prefetch. Fix: pack pA*->bA* (32 f32 -> 8 dwords) BEFORE
// issuing the next prefetch; copies deleted. Live ~205 = round-4 level.

typedef __attribute__((ext_vector_type(8))) short short8;
typedef __attribute__((ext_vector_type(4))) float f32x4;
typedef __attribute__((ext_vector_type(2))) float f32x2;
typedef __attribute__((ext_vector_type(2))) unsigned int u32x2;
typedef __attribute__((ext_vector_type(4))) unsigned int u32x4;

#define NODES 16384
#define NPB   16
#define NBLK  (NODES / NPB)

#define MFMA16(a, b, c) __builtin_amdgcn_mfma_f32_16x16x32_bf16((a), (b), (c), 0, 0, 0)

__device__ __forceinline__ unsigned short f2bf(float f) {
  unsigned int u = __float_as_uint(f);
  u += 0x7FFFu + ((u >> 16) & 1u);
  return (unsigned short)(u >> 16);
}
__device__ __forceinline__ unsigned int pk2(float lo, float hi) {
  unsigned int a = __float_as_uint(hi) + 0x8000u;
  unsigned int b = __float_as_uint(lo) + 0x8000u;
  return __builtin_amdgcn_perm(a, b, 0x07060302u);
}
__device__ __forceinline__ float bfl(unsigned int u) { return __uint_as_float(u << 16); }
__device__ __forceinline__ float bfh(unsigned int u) { return __uint_as_float(u & 0xFFFF0000u); }
__device__ __forceinline__ float silu_f(float x) {
  return x * __builtin_amdgcn_rcpf(1.f + __expf(-x));
}
__device__ __forceinline__ f32x4 silu4(f32x4 x) {
  f32x4 r; r[0]=silu_f(x[0]); r[1]=silu_f(x[1]); r[2]=silu_f(x[2]); r[3]=silu_f(x[3]); return r;
}
__device__ __forceinline__ short8 packb(f32x4 a, f32x4 b) {
  u32x4 t;
  t[0] = pk2(a[0], a[1]); t[1] = pk2(a[2], a[3]);
  t[2] = pk2(b[0], b[1]); t[3] = pk2(b[2], b[3]);
  return __builtin_bit_cast(short8, t);
}
__device__ __forceinline__ short8 ldfragT(const float* __restrict__ W, int k0, int col) {
  short8 r;
  #pragma unroll
  for (int m = 0; m < 8; m++) r[m] = (short)f2bf(W[(k0 + m) * 64 + col]);
  return r;
}

__global__ __launch_bounds__(256, 2) void egnn_mfma(
    const float* __restrict__ ped, const float* __restrict__ h_st,
    const float* __restrict__ h_neigh, const float* __restrict__ rela,
    const unsigned char* __restrict__ mask8,
    const float* __restrict__ We1, const float* __restrict__ be1,
    const float* __restrict__ We2, const float* __restrict__ be2,
    const float* __restrict__ Wx1, const float* __restrict__ bx1,
    const float* __restrict__ Wx2, const float* __restrict__ bx2,
    const float* __restrict__ Wh1, const float* __restrict__ bh1,
    const float* __restrict__ Wh2, const float* __restrict__ bh2,
    float* __restrict__ out)
{
  __shared__ __align__(16) float s_hst[16][64];
  __shared__ __align__(16) float s_u[16][64];
  __shared__ __align__(16) float s_miw[4][16][64];
  __shared__ __align__(16) unsigned int s_scr[4][2][16][36];  // per-wave, per-parity
  __shared__ float s_cvec[2][64];     // be2, bx1
  __shared__ float s_w1l[64];         // We1 dist row
  __shared__ float s_wx2[64];         // Wx2
  __shared__ float s_aggx[4][16], s_aggy[4][16], s_nn[4][16];
  __shared__ int s_flags[2];

  const int t  = threadIdx.x;
  const int l  = t & 63;
  const int w  = t >> 6;
  const int lg = l >> 4;
  const int jl = l & 15;
  const int base = blockIdx.x * NPB;

  if (t == 0) { s_flags[0] = 1; s_flags[1] = 1; }
  __syncthreads();
  {
    const unsigned int* mw = (const unsigned int*)mask8;
    unsigned int iok = 1, fok = 1;
    #pragma unroll
    for (int q = 0; q < 4; q++) {
      unsigned int v = mw[t * 4 + q];
      if (v > 1u) iok = 0;
      if (v != 0u && v != 0x3F800000u) fok = 0;
    }
    if (!iok) atomicAnd(&s_flags[0], 0);
    if (!fok) atomicAnd(&s_flags[1], 0);
  }
  {
    const f32x4* src = (const f32x4*)(h_st + (size_t)base * 64);
    f32x4* dst = (f32x4*)&s_hst[0][0];
    dst[t] = src[t];
    if (t < 64)        s_cvec[0][t] = be2[t];
    else if (t < 128)  s_cvec[1][t - 64] = bx1[t - 64];
    else if (t < 192)  s_w1l[t - 128] = We1[128 * 64 + (t - 128)];
    else               s_wx2[t - 192] = Wx2[t - 192];
  }
  __syncthreads();
  const int mode = s_flags[0] ? 0 : (s_flags[1] ? 1 : 2);

  auto ldmask = [&](size_t idx) -> float {
    if (mode == 0)      return (((const int*)mask8)[idx] != 0) ? 1.f : 0.f;
    else if (mode == 1) return (((const float*)mask8)[idx] != 0.f) ? 1.f : 0.f;
    else                return (mask8[idx] != 0) ? 1.f : 0.f;
  };

  // ---- U = be1 + h_st @ We1[0:64] ----
  {
    f32x4 uacc = {0.f, 0.f, 0.f, 0.f};
    #pragma unroll
    for (int kk = 0; kk < 2; kk++) {
      short8 au = ldfragT(We1, 8 * lg + 32 * kk, 16 * w + jl);
      f32x4 q0 = *(const f32x4*)&s_hst[jl][8 * lg + 32 * kk];
      f32x4 q1 = *(const f32x4*)&s_hst[jl][8 * lg + 32 * kk + 4];
      uacc = MFMA16(au, packb(q0, q1), uacc);
    }
    f32x4 b1v = *(const f32x4*)(be1 + 16 * w + 4 * lg);
    *(f32x4*)&s_u[jl][16 * w + 4 * lg] = uacc + b1v;
  }

  // ---- preload weight A-fragments (96 regs, mostly AGPR-shelved) ----
  short8 a1[4][2], a2[4][2], a3[4][2];
  #pragma unroll
  for (int mt = 0; mt < 4; mt++)
    #pragma unroll
    for (int kk = 0; kk < 2; kk++) {
      a1[mt][kk] = ldfragT(We1 + 64 * 64, 8 * lg + 32 * kk, 16 * mt + jl);
      a2[mt][kk] = ldfragT(We2,           8 * lg + 32 * kk, 16 * mt + jl);
      a3[mt][kk] = ldfragT(Wx1,           8 * lg + 32 * kk, 16 * mt + jl);
    }
  const float bx2s = bx2[0];

  // ---- prefetch pair 0 ----
  const float* hn_lane = h_neigh + ((size_t)base * 64 + 16 * w + jl) * 64 + 8 * lg;
  const size_t ro = (size_t)base * 64 + 16 * w + jl;
  f32x4 pA0, pA1, pA2, pA3, pB0, pB1, pB2, pB3;
  f32x2 prA, prB; float pmA, pmB;
  {
    const float* qA = hn_lane;
    const float* qB = hn_lane + 4096;
    pA0 = *(const f32x4*)(qA + 0);  pA1 = *(const f32x4*)(qA + 4);
    pA2 = *(const f32x4*)(qA + 32); pA3 = *(const f32x4*)(qA + 36);
    pB0 = *(const f32x4*)(qB + 0);  pB1 = *(const f32x4*)(qB + 4);
    pB2 = *(const f32x4*)(qB + 32); pB3 = *(const f32x4*)(qB + 36);
    prA = *(const f32x2*)(rela + ro * 6);
    prB = *(const f32x2*)(rela + (ro + 64) * 6);
    pmA = ldmask(ro);
    pmB = ldmask(ro + 64);
  }
  __syncthreads();  // s_u ready

  // =========================== main loop (2 nodes/iter) ===========================
  #pragma unroll 1
  for (int np = 0; np < NPB / 2; np++) {
    const int nA = 2 * np, nB = nA + 1;
    // pack FIRST: pA*/pB* die here, before the next prefetch is issued
    const short8 bA0 = packb(pA0, pA1), bA1 = packb(pA2, pA3);
    const short8 bB0 = packb(pB0, pB1), bB1 = packb(pB2, pB3);
    const f32x2 rrA = prA, rrB = prB;
    const float mfA = pmA, mfB = pmB;
    if (np < NPB / 2 - 1) {
      const float* qA = hn_lane + (size_t)(nA + 2) * 4096;
      const float* qB = hn_lane + (size_t)(nB + 2) * 4096;
      pA0 = *(const f32x4*)(qA + 0);  pA1 = *(const f32x4*)(qA + 4);
      pA2 = *(const f32x4*)(qA + 32); pA3 = *(const f32x4*)(qA + 36);
      pB0 = *(const f32x4*)(qB + 0);  pB1 = *(const f32x4*)(qB + 4);
      pB2 = *(const f32x4*)(qB + 32); pB3 = *(const f32x4*)(qB + 36);
      prA = *(const f32x2*)(rela + (ro + (size_t)(nA + 2) * 64) * 6);
      prB = *(const f32x2*)(rela + (ro + (size_t)(nB + 2) * 64) * 6);
      pmA = ldmask(ro + (size_t)(nA + 2) * 64);
      pmB = ldmask(ro + (size_t)(nB + 2) * 64);
    }
    const float dA = sqrtf(rrA[0] * rrA[0] + rrA[1] * rrA[1]);
    const float dB = sqrtf(rrB[0] * rrB[0] + rrB[1] * rrB[1]);

    float msA = mfA, msB = mfB;
    msA += __shfl_xor(msA, 1, 64); msB += __shfl_xor(msB, 1, 64);
    msA += __shfl_xor(msA, 2, 64); msB += __shfl_xor(msB, 2, 64);
    msA += __shfl_xor(msA, 4, 64); msB += __shfl_xor(msB, 4, 64);
    msA += __shfl_xor(msA, 8, 64); msB += __shfl_xor(msB, 8, 64);
    if (l == 0) { s_nn[w][nA] = msA; s_nn[w][nB] = msB; }

    // ---- Phase 1: GEMM1 (A,B interleaved) ----
    f32x4 aA[4], aB[4];
    #pragma unroll
    for (int ht = 0; ht < 4; ht++) {
      const f32x4 wl = *(const f32x4*)&s_w1l[16 * ht + 4 * lg];
      aA[ht] = *(const f32x4*)&s_u[nA][16 * ht + 4 * lg] + dA * wl;
      aB[ht] = *(const f32x4*)&s_u[nB][16 * ht + 4 * lg] + dB * wl;
      aA[ht] = MFMA16(a1[ht][0], bA0, aA[ht]);
      aB[ht] = MFMA16(a1[ht][0], bB0, aB[ht]);
      aA[ht] = MFMA16(a1[ht][1], bA1, aA[ht]);
      aB[ht] = MFMA16(a1[ht][1], bB1, aB[ht]);
    }
    #pragma unroll
    for (int ht = 0; ht < 4; ht++) {
      f32x4 eA = silu4(aA[ht]);
      f32x4 eB = silu4(aB[ht]);
      u32x2 wA; wA[0] = pk2(eA[0], eA[1]); wA[1] = pk2(eA[2], eA[3]);
      u32x2 wB; wB[0] = pk2(eB[0], eB[1]); wB[1] = pk2(eB[2], eB[3]);
      *(u32x2*)&s_scr[w][0][jl][8 * ht + 2 * lg] = wA;
      *(u32x2*)&s_scr[w][1][jl][8 * ht + 2 * lg] = wB;
    }
    short8 b2A0 = *(const short8*)&s_scr[w][0][jl][4 * lg];
    short8 b2A1 = *(const short8*)&s_scr[w][0][jl][16 + 4 * lg];
    short8 b2B0 = *(const short8*)&s_scr[w][1][jl][4 * lg];
    short8 b2B1 = *(const short8*)&s_scr[w][1][jl][16 + 4 * lg];

    // ---- Phase 2a: GEMM2 (both) ----
    #pragma unroll
    for (int ht = 0; ht < 4; ht++) {
      const f32x4 c2 = *(const f32x4*)&s_cvec[0][16 * ht + 4 * lg];
      aA[ht] = MFMA16(a2[ht][0], b2A0, c2);
      aB[ht] = MFMA16(a2[ht][0], b2B0, c2);
      aA[ht] = MFMA16(a2[ht][1], b2A1, aA[ht]);
      aB[ht] = MFMA16(a2[ht][1], b2B1, aB[ht]);
    }
    #pragma unroll
    for (int ht = 0; ht < 4; ht++) {
      f32x4 mA = silu4(aA[ht]) * mfA;
      f32x4 mB = silu4(aB[ht]) * mfB;
      u32x2 wA; wA[0] = pk2(mA[0], mA[1]); wA[1] = pk2(mA[2], mA[3]);
      u32x2 wB; wB[0] = pk2(mB[0], mB[1]); wB[1] = pk2(mB[2], mB[3]);
      *(u32x2*)&s_scr[w][0][jl][8 * ht + 2 * lg] = wA;
      *(u32x2*)&s_scr[w][1][jl][8 * ht + 2 * lg] = wB;
    }
    short8 b3A0 = *(const short8*)&s_scr[w][0][jl][4 * lg];
    short8 b3A1 = *(const short8*)&s_scr[w][0][jl][16 + 4 * lg];
    short8 b3B0 = *(const short8*)&s_scr[w][1][jl][4 * lg];
    short8 b3B1 = *(const short8*)&s_scr[w][1][jl][16 + 4 * lg];

    // ---- m_i partials (both) ----
    {
      const int hw = l & 31, jh = l >> 5;
      float peA = 0.f, poA = 0.f, peB = 0.f, poB = 0.f;
      #pragma unroll
      for (int c = 0; c < 8; c++) {
        unsigned int vA = s_scr[w][0][8 * jh + c][hw];
        unsigned int vB = s_scr[w][1][8 * jh + c][hw];
        peA += bfl(vA); poA += bfh(vA);
        peB += bfl(vB); poB += bfh(vB);
      }
      peA += __shfl_xor(peA, 32, 64); poA += __shfl_xor(poA, 32, 64);
      peB += __shfl_xor(peB, 32, 64); poB += __shfl_xor(poB, 32, 64);
      if (l < 32) {
        f32x2 vA; vA[0] = peA; vA[1] = poA;
        f32x2 vB; vB[0] = peB; vB[1] = poB;
        *(f32x2*)&s_miw[w][nA][2 * hw] = vA;
        *(f32x2*)&s_miw[w][nB][2 * hw] = vB;
      }
    }

    // ---- Phase 2b: GEMM3 (both) + gates ----
    #pragma unroll
    for (int ht = 0; ht < 4; ht++) {
      const f32x4 c3 = *(const f32x4*)&s_cvec[1][16 * ht + 4 * lg];
      aA[ht] = MFMA16(a3[ht][0], b3A0, c3);
      aB[ht] = MFMA16(a3[ht][0], b3B0, c3);
      aA[ht] = MFMA16(a3[ht][1], b3A1, aA[ht]);
      aB[ht] = MFMA16(a3[ht][1], b3B1, aB[ht]);
    }
    float ggA = 0.f, ggB = 0.f;
    #pragma unroll
    for (int ht = 0; ht < 4; ht++) {
      const f32x4 wx = *(const f32x4*)&s_wx2[16 * ht + 4 * lg];
      f32x4 gA = silu4(aA[ht]);
      f32x4 gB = silu4(aB[ht]);
      ggA += gA[0] * wx[0] + gA[1] * wx[1] + gA[2] * wx[2] + gA[3] * wx[3];
      ggB += gB[0] * wx[0] + gB[1] * wx[1] + gB[2] * wx[2] + gB[3] * wx[3];
    }
    ggA += __shfl_xor(ggA, 16, 64); ggB += __shfl_xor(ggB, 16, 64);
    ggA += __shfl_xor(ggA, 32, 64); ggB += __shfl_xor(ggB, 32, 64);
    const float gateA = ggA + bx2s;
    const float gateB = ggB + bx2s;

    float axA = rrA[0] * gateA, ayA = rrA[1] * gateA;
    float axB = rrB[0] * gateB, ayB = rrB[1] * gateB;
    axA += __shfl_xor(axA, 1, 64); ayA += __shfl_xor(ayA, 1, 64);
    axB += __shfl_xor(axB, 1, 64); ayB += __shfl_xor(ayB, 1, 64);
    axA += __shfl_xor(axA, 2, 64); ayA += __shfl_xor(ayA, 2, 64);
    axB += __shfl_xor(axB, 2, 64); ayB += __shfl_xor(ayB, 2, 64);
    axA += __shfl_xor(axA, 4, 64); ayA += __shfl_xor(ayA, 4, 64);
    axB += __shfl_xor(axB, 4, 64); ayB += __shfl_xor(ayB, 4, 64);
    axA += __shfl_xor(axA, 8, 64); ayA += __shfl_xor(ayA, 8, 64);
    axB += __shfl_xor(axB, 8, 64); ayB += __shfl_xor(ayB, 8, 64);
    if (l == 0) {
      s_aggx[w][nA] = axA; s_aggy[w][nA] = ayA;
      s_aggx[w][nB] = axB; s_aggy[w][nB] = ayB;
    }
  }
  __syncthreads();

  // ---- x_new ----
  if (t < 32) {
    const int node = t >> 1, c = t & 1;
    const float nn = s_nn[0][node] + s_nn[1][node] + s_nn[2][node] + s_nn[3][node];
    const float ag = (c ? (s_aggy[0][node] + s_aggy[1][node] + s_aggy[2][node] + s_aggy[3][node])
                        : (s_aggx[0][node] + s_aggx[1][node] + s_aggx[2][node] + s_aggx[3][node]));
    out[(size_t)(base + node) * 2 + c] =
        ped[(size_t)(base + node) * 2 + c] + ag / (nn + 1e-6f);
  }

  // ---- f_h batched over 16 nodes ----
  {
    f32x4 hacc = *(const f32x4*)(bh1 + 16 * w + 4 * lg);
    #pragma unroll
    for (int kk = 0; kk < 4; kk++) {
      short8 ah = ldfragT(Wh1, 8 * lg + 32 * kk, 16 * w + jl);
      f32x4 q0, q1;
      if (kk < 2) {
        q0 = *(const f32x4*)&s_hst[jl][8 * lg + 32 * kk];
        q1 = *(const f32x4*)&s_hst[jl][8 * lg + 32 * kk + 4];
      } else {
        const int off = 8 * lg + 32 * (kk - 2);
        q0 = *(const f32x4*)&s_miw[0][jl][off]     + *(const f32x4*)&s_miw[1][jl][off]
           + *(const f32x4*)&s_miw[2][jl][off]     + *(const f32x4*)&s_miw[3][jl][off];
        q1 = *(const f32x4*)&s_miw[0][jl][off + 4] + *(const f32x4*)&s_miw[1][jl][off + 4]
           + *(const f32x4*)&s_miw[2][jl][off + 4] + *(const f32x4*)&s_miw[3][jl][off + 4];
      }
      hacc = MFMA16(ah, packb(q0, q1), hacc);
    }
    f32x4 h1 = silu4(hacc);
    u32x2 wv; wv[0] = pk2(h1[0], h1[1]); wv[1] = pk2(h1[2], h1[3]);
    *(u32x2*)&s_scr[0][0][jl][8 * w + 2 * lg] = wv;
  }
  __syncthreads();
  {
    short8 hb0 = *(const short8*)&s_scr[0][0][jl][4 * lg];
    short8 hb1 = *(const short8*)&s_scr[0][0][jl][16 + 4 * lg];
    short8 aw0 = ldfragT(Wh2, 8 * lg,      16 * w + jl);
    short8 aw1 = ldfragT(Wh2, 8 * lg + 32, 16 * w + jl);
    f32x4 oacc = *(const f32x4*)(bh2 + 16 * w + 4 * lg);
    oacc = MFMA16(aw0, hb0, oacc);
    oacc = MFMA16(aw1, hb1, oacc);
    f32x4 res = oacc + *(const f32x4*)&s_hst[jl][16 * w + 4 * lg];
    *(f32x4*)(out + 32768 + (size_t)(base + jl) * 64 + 16 * w + 4 * lg) = res;
  }
}

extern "C" void kernel_launch(void* const* d_in, const int* in_sizes, int n_in,
                              void* d_out, int out_size, void* d_ws, size_t ws_size,
                              hipStream_t stream) {
  (void)in_sizes; (void)n_in; (void)out_size; (void)d_ws; (void)ws_size;
  const float* ped     = (const float*)d_in[0];
  const float* h_st    = (const float*)d_in[1];
  const float* h_neigh = (const float*)d_in[2];
  const float* rela    = (const float*)d_in[3];
  const unsigned char* mask = (const unsigned char*)d_in[4];
  const float* We1 = (const float*)d_in[5];  const float* be1 = (const float*)d_in[6];
  const float* We2 = (const float*)d_in[7];  const float* be2 = (const float*)d_in[8];
  const float* Wx1 = (const float*)d_in[9];  const float* bx1 = (const float*)d_in[10];
  const float* Wx2 = (const float*)d_in[11]; const float* bx2 = (const float*)d_in[12];
  const float* Wh1 = (const float*)d_in[13]; const float* bh1 = (const float*)d_in[14];
  const float* Wh2 = (const float*)d_in[15]; const float* bh2 = (const float*)d_in[16];

  hipLaunchKernelGGL(egnn_mfma, dim3(NBLK), dim3(256), 0, stream,
                     ped, h_st, h_neigh, rela, mask,
                     We1, be1, We2, be2, Wx1, bx1, Wx2, bx2,
                     Wh1, bh1, Wh2, bh2, (float*)d_out);
}

// Round 8
// 117.470 us; speedup vs baseline: 2.4147x; 1.7760x over previous
//
#include <hip/hip_runtime.h>
#include <hip/hip_bf16.h>

// ConvEGNN3 round 8: round-6 LDS-weight structure at (256,2) + stride-40 scratch.
// Evidence: r4=140us @2 waves/SIMD latency-bound; r6 structure passed but
// (256,3) forced 84V/86A split -> spill. Here: same LDS-weight diet (a2/a3
// JIT-loaded from LDS, w1l/wx2/cvec in LDS, a1 in regs/AGPR) with the safe
// (256,2) bound -> live ~125-150 total regs; if <=168, HW grants 3 waves/SIMD.
// s_scr row stride 36->40 words: writes hit 32 banks exactly once per
// 16-lane phase, b128 reads hit each 4-bank group exactly twice (minimum).

typedef __attribute__((ext_vector_type(8))) short short8;
typedef __attribute__((ext_vector_type(4))) float f32x4;
typedef __attribute__((ext_vector_type(2))) float f32x2;
typedef __attribute__((ext_vector_type(2))) unsigned int u32x2;
typedef __attribute__((ext_vector_type(4))) unsigned int u32x4;

#define NODES 16384
#define NPB   16
#define NBLK  (NODES / NPB)

#define MFMA16(a, b, c) __builtin_amdgcn_mfma_f32_16x16x32_bf16((a), (b), (c), 0, 0, 0)

__device__ __forceinline__ unsigned short f2bf(float f) {
  unsigned int u = __float_as_uint(f);
  u += 0x7FFFu + ((u >> 16) & 1u);
  return (unsigned short)(u >> 16);
}
__device__ __forceinline__ unsigned int pk2(float lo, float hi) {
  unsigned int a = __float_as_uint(hi) + 0x8000u;
  unsigned int b = __float_as_uint(lo) + 0x8000u;
  return __builtin_amdgcn_perm(a, b, 0x07060302u);
}
__device__ __forceinline__ float bfl(unsigned int u) { return __uint_as_float(u << 16); }
__device__ __forceinline__ float bfh(unsigned int u) { return __uint_as_float(u & 0xFFFF0000u); }
__device__ __forceinline__ float silu_f(float x) {
  return x * __builtin_amdgcn_rcpf(1.f + __expf(-x));
}
__device__ __forceinline__ f32x4 silu4(f32x4 x) {
  f32x4 r; r[0]=silu_f(x[0]); r[1]=silu_f(x[1]); r[2]=silu_f(x[2]); r[3]=silu_f(x[3]); return r;
}
__device__ __forceinline__ short8 packb(f32x4 a, f32x4 b) {
  u32x4 t;
  t[0] = pk2(a[0], a[1]); t[1] = pk2(a[2], a[3]);
  t[2] = pk2(b[0], b[1]); t[3] = pk2(b[2], b[3]);
  return __builtin_bit_cast(short8, t);
}
__device__ __forceinline__ short8 ldfragT(const float* __restrict__ W, int k0, int col) {
  short8 r;
  #pragma unroll
  for (int m = 0; m < 8; m++) r[m] = (short)f2bf(W[(k0 + m) * 64 + col]);
  return r;
}

__global__ __launch_bounds__(256, 2) void egnn_mfma(
    const float* __restrict__ ped, const float* __restrict__ h_st,
    const float* __restrict__ h_neigh, const float* __restrict__ rela,
    const unsigned char* __restrict__ mask8,
    const float* __restrict__ We1, const float* __restrict__ be1,
    const float* __restrict__ We2, const float* __restrict__ be2,
    const float* __restrict__ Wx1, const float* __restrict__ bx1,
    const float* __restrict__ Wx2, const float* __restrict__ bx2,
    const float* __restrict__ Wh1, const float* __restrict__ bh1,
    const float* __restrict__ Wh2, const float* __restrict__ bh2,
    float* __restrict__ out)
{
  __shared__ __align__(16) float s_hst[16][64];
  __shared__ __align__(16) float s_u[16][64];
  __shared__ __align__(16) float s_miw[4][16][64];
  __shared__ __align__(16) unsigned int s_scr[4][16][40];   // stride 40: bank-optimal
  __shared__ __align__(16) short8 s_af[16][64];   // c = 8*g + 2*mt + kk; g0=We2, g1=Wx1
  __shared__ float s_cvec[2][64];   // be2, bx1
  __shared__ float s_w1l[64];       // We1 dist row
  __shared__ float s_wx2[64];       // Wx2
  __shared__ float s_aggx[4][16], s_aggy[4][16], s_nn[4][16];
  __shared__ int s_flags[2];

  const int t  = threadIdx.x;
  const int l  = t & 63;
  const int w  = t >> 6;
  const int lg = l >> 4;
  const int jl = l & 15;
  const int base = blockIdx.x * NPB;

  if (t == 0) { s_flags[0] = 1; s_flags[1] = 1; }
  __syncthreads();
  {
    const unsigned int* mw = (const unsigned int*)mask8;
    unsigned int iok = 1, fok = 1;
    #pragma unroll
    for (int q = 0; q < 4; q++) {
      unsigned int v = mw[t * 4 + q];
      if (v > 1u) iok = 0;
      if (v != 0u && v != 0x3F800000u) fok = 0;
    }
    if (!iok) atomicAnd(&s_flags[0], 0);
    if (!fok) atomicAnd(&s_flags[1], 0);
  }
  {
    const f32x4* src = (const f32x4*)(h_st + (size_t)base * 64);
    f32x4* dst = (f32x4*)&s_hst[0][0];
    dst[t] = src[t];
    if (t < 64)        s_cvec[0][t] = be2[t];
    else if (t < 128)  s_cvec[1][t - 64] = bx1[t - 64];
    else if (t < 192)  s_w1l[t - 128] = We1[128 * 64 + (t - 128)];
    else               s_wx2[t - 192] = Wx2[t - 192];
  }
  // stage a2/a3 fragments into LDS: wave w stages combos 4w..4w+3
  #pragma unroll
  for (int ci = 0; ci < 4; ci++) {
    const int c  = 4 * w + ci;
    const int g  = c >> 3, mt = (c >> 1) & 3, kk = c & 1;
    const float* W = g ? Wx1 : We2;
    s_af[c][l] = ldfragT(W, 8 * lg + 32 * kk, 16 * mt + jl);
  }
  __syncthreads();
  const int mode = s_flags[0] ? 0 : (s_flags[1] ? 1 : 2);

  auto ldmask = [&](size_t idx) -> float {
    if (mode == 0)      return (((const int*)mask8)[idx] != 0) ? 1.f : 0.f;
    else if (mode == 1) return (((const float*)mask8)[idx] != 0.f) ? 1.f : 0.f;
    else                return (mask8[idx] != 0) ? 1.f : 0.f;
  };

  // ---- U = be1 + h_st @ We1[0:64] ----
  {
    f32x4 uacc = {0.f, 0.f, 0.f, 0.f};
    #pragma unroll
    for (int kk = 0; kk < 2; kk++) {
      short8 au = ldfragT(We1, 8 * lg + 32 * kk, 16 * w + jl);
      f32x4 q0 = *(const f32x4*)&s_hst[jl][8 * lg + 32 * kk];
      f32x4 q1 = *(const f32x4*)&s_hst[jl][8 * lg + 32 * kk + 4];
      uacc = MFMA16(au, packb(q0, q1), uacc);
    }
    f32x4 b1v = *(const f32x4*)(be1 + 16 * w + 4 * lg);
    *(f32x4*)&s_u[jl][16 * w + 4 * lg] = uacc + b1v;
  }

  // ---- a1 (We1 lower) fragments stay in registers/AGPR (used first) ----
  short8 a1[4][2];
  #pragma unroll
  for (int mt = 0; mt < 4; mt++)
    #pragma unroll
    for (int kk = 0; kk < 2; kk++)
      a1[mt][kk] = ldfragT(We1 + 64 * 64, 8 * lg + 32 * kk, 16 * mt + jl);
  const float bx2s = bx2[0];

  // ---- initial prefetch (node 0) ----
  const float* hn_lane = h_neigh + ((size_t)base * 64 + 16 * w + jl) * 64 + 8 * lg;
  const size_t ro = (size_t)base * 64 + 16 * w + jl;
  f32x4 pf0 = *(const f32x4*)(hn_lane + 0);
  f32x4 pf1 = *(const f32x4*)(hn_lane + 4);
  f32x4 pf2 = *(const f32x4*)(hn_lane + 32);
  f32x4 pf3 = *(const f32x4*)(hn_lane + 36);
  f32x2 pre = *(const f32x2*)(rela + ro * 6);
  float pmf = ldmask(ro);
  __syncthreads();  // s_u + s_af ready

  // =========================== main loop ===========================
  #pragma unroll 1
  for (int nl = 0; nl < NPB; nl++) {
    // pack FIRST so pf* die before next prefetch issues
    const short8 b1k0 = packb(pf0, pf1);
    const short8 b1k1 = packb(pf2, pf3);
    const f32x2 rr = pre; const float mf = pmf;
    if (nl < NPB - 1) {
      const float* p = hn_lane + (size_t)(nl + 1) * 4096;
      pf0 = *(const f32x4*)(p + 0);  pf1 = *(const f32x4*)(p + 4);
      pf2 = *(const f32x4*)(p + 32); pf3 = *(const f32x4*)(p + 36);
      pre = *(const f32x2*)(rela + (ro + (size_t)(nl + 1) * 64) * 6);
      pmf = ldmask(ro + (size_t)(nl + 1) * 64);
    }
    const float d = sqrtf(rr[0] * rr[0] + rr[1] * rr[1]);

    float msum = mf;
    msum += __shfl_xor(msum, 1, 64); msum += __shfl_xor(msum, 2, 64);
    msum += __shfl_xor(msum, 4, 64); msum += __shfl_xor(msum, 8, 64);
    if (l == 0) s_nn[w][nl] = msum;

    // ---- GEMM1: E^T ----
    f32x4 acc[4];
    #pragma unroll
    for (int ht = 0; ht < 4; ht++) {
      const f32x4 wl = *(const f32x4*)&s_w1l[16 * ht + 4 * lg];
      acc[ht] = *(const f32x4*)&s_u[nl][16 * ht + 4 * lg] + d * wl;
      acc[ht] = MFMA16(a1[ht][0], b1k0, acc[ht]);
      acc[ht] = MFMA16(a1[ht][1], b1k1, acc[ht]);
    }
    #pragma unroll
    for (int ht = 0; ht < 4; ht++) {
      f32x4 e = silu4(acc[ht]);
      u32x2 wv; wv[0] = pk2(e[0], e[1]); wv[1] = pk2(e[2], e[3]);
      *(u32x2*)&s_scr[w][jl][8 * ht + 2 * lg] = wv;
    }
    short8 b2k0 = *(const short8*)&s_scr[w][jl][4 * lg];
    short8 b2k1 = *(const short8*)&s_scr[w][jl][16 + 4 * lg];

    // ---- GEMM2: M^T (a2 fragments JIT from LDS) ----
    #pragma unroll
    for (int ht = 0; ht < 4; ht++) {
      const short8 f2k0 = s_af[2 * ht][l];
      const short8 f2k1 = s_af[2 * ht + 1][l];
      acc[ht] = *(const f32x4*)&s_cvec[0][16 * ht + 4 * lg];
      acc[ht] = MFMA16(f2k0, b2k0, acc[ht]);
      acc[ht] = MFMA16(f2k1, b2k1, acc[ht]);
    }
    #pragma unroll
    for (int ht = 0; ht < 4; ht++) {
      f32x4 m = silu4(acc[ht]) * mf;
      u32x2 wv; wv[0] = pk2(m[0], m[1]); wv[1] = pk2(m[2], m[3]);
      *(u32x2*)&s_scr[w][jl][8 * ht + 2 * lg] = wv;
    }
    short8 b3k0 = *(const short8*)&s_scr[w][jl][4 * lg];
    short8 b3k1 = *(const short8*)&s_scr[w][jl][16 + 4 * lg];

    // m_i partial
    {
      const int hw = l & 31, jh = l >> 5;
      float pe = 0.f, po = 0.f;
      #pragma unroll
      for (int c = 0; c < 8; c++) {
        unsigned int v = s_scr[w][8 * jh + c][hw];
        pe += bfl(v); po += bfh(v);
      }
      pe += __shfl_xor(pe, 32, 64);
      po += __shfl_xor(po, 32, 64);
      if (l < 32) {
        f32x2 v2; v2[0] = pe; v2[1] = po;
        *(f32x2*)&s_miw[w][nl][2 * hw] = v2;
      }
    }

    // ---- GEMM3: G^T + gate (a3 fragments JIT from LDS) ----
    #pragma unroll
    for (int ht = 0; ht < 4; ht++) {
      const short8 f3k0 = s_af[8 + 2 * ht][l];
      const short8 f3k1 = s_af[8 + 2 * ht + 1][l];
      acc[ht] = *(const f32x4*)&s_cvec[1][16 * ht + 4 * lg];
      acc[ht] = MFMA16(f3k0, b3k0, acc[ht]);
      acc[ht] = MFMA16(f3k1, b3k1, acc[ht]);
    }
    float gg = 0.f;
    #pragma unroll
    for (int ht = 0; ht < 4; ht++) {
      const f32x4 wx = *(const f32x4*)&s_wx2[16 * ht + 4 * lg];
      f32x4 g = silu4(acc[ht]);
      gg += g[0] * wx[0] + g[1] * wx[1] + g[2] * wx[2] + g[3] * wx[3];
    }
    gg += __shfl_xor(gg, 16, 64);
    gg += __shfl_xor(gg, 32, 64);
    const float gate = gg + bx2s;

    float ax = rr[0] * gate, ay = rr[1] * gate;
    ax += __shfl_xor(ax, 1, 64); ay += __shfl_xor(ay, 1, 64);
    ax += __shfl_xor(ax, 2, 64); ay += __shfl_xor(ay, 2, 64);
    ax += __shfl_xor(ax, 4, 64); ay += __shfl_xor(ay, 4, 64);
    ax += __shfl_xor(ax, 8, 64); ay += __shfl_xor(ay, 8, 64);
    if (l == 0) { s_aggx[w][nl] = ax; s_aggy[w][nl] = ay; }
  }
  __syncthreads();

  // ---- x_new ----
  if (t < 32) {
    const int node = t >> 1, c = t & 1;
    const float nn = s_nn[0][node] + s_nn[1][node] + s_nn[2][node] + s_nn[3][node];
    const float ag = (c ? (s_aggy[0][node] + s_aggy[1][node] + s_aggy[2][node] + s_aggy[3][node])
                        : (s_aggx[0][node] + s_aggx[1][node] + s_aggx[2][node] + s_aggx[3][node]));
    out[(size_t)(base + node) * 2 + c] =
        ped[(size_t)(base + node) * 2 + c] + ag / (nn + 1e-6f);
  }

  // ---- f_h batched over 16 nodes ----
  {
    f32x4 hacc = *(const f32x4*)(bh1 + 16 * w + 4 * lg);
    #pragma unroll
    for (int kk = 0; kk < 4; kk++) {
      short8 ah = ldfragT(Wh1, 8 * lg + 32 * kk, 16 * w + jl);
      f32x4 q0, q1;
      if (kk < 2) {
        q0 = *(const f32x4*)&s_hst[jl][8 * lg + 32 * kk];
        q1 = *(const f32x4*)&s_hst[jl][8 * lg + 32 * kk + 4];
      } else {
        const int off = 8 * lg + 32 * (kk - 2);
        q0 = *(const f32x4*)&s_miw[0][jl][off]     + *(const f32x4*)&s_miw[1][jl][off]
           + *(const f32x4*)&s_miw[2][jl][off]     + *(const f32x4*)&s_miw[3][jl][off];
        q1 = *(const f32x4*)&s_miw[0][jl][off + 4] + *(const f32x4*)&s_miw[1][jl][off + 4]
           + *(const f32x4*)&s_miw[2][jl][off + 4] + *(const f32x4*)&s_miw[3][jl][off + 4];
      }
      hacc = MFMA16(ah, packb(q0, q1), hacc);
    }
    f32x4 h1 = silu4(hacc);
    u32x2 wv; wv[0] = pk2(h1[0], h1[1]); wv[1] = pk2(h1[2], h1[3]);
    *(u32x2*)&s_scr[0][jl][8 * w + 2 * lg] = wv;
  }
  __syncthreads();
  {
    short8 hb0 = *(const short8*)&s_scr[0][jl][4 * lg];
    short8 hb1 = *(const short8*)&s_scr[0][jl][16 + 4 * lg];
    short8 aw0 = ldfragT(Wh2, 8 * lg,      16 * w + jl);
    short8 aw1 = ldfragT(Wh2, 8 * lg + 32, 16 * w + jl);
    f32x4 oacc = *(const f32x4*)(bh2 + 16 * w + 4 * lg);
    oacc = MFMA16(aw0, hb0, oacc);
    oacc = MFMA16(aw1, hb1, oacc);
    f32x4 res = oacc + *(const f32x4*)&s_hst[jl][16 * w + 4 * lg];
    *(f32x4*)(out + 32768 + (size_t)(base + jl) * 64 + 16 * w + 4 * lg) = res;
  }
}

extern "C" void kernel_launch(void* const* d_in, const int* in_sizes, int n_in,
                              void* d_out, int out_size, void* d_ws, size_t ws_size,
                              hipStream_t stream) {
  (void)in_sizes; (void)n_in; (void)out_size; (void)d_ws; (void)ws_size;
  const float* ped     = (const float*)d_in[0];
  const float* h_st    = (const float*)d_in[1];
  const float* h_neigh = (const float*)d_in[2];
  const float* rela    = (const float*)d_in[3];
  const unsigned char* mask = (const unsigned char*)d_in[4];
  const float* We1 = (const float*)d_in[5];  const float* be1 = (const float*)d_in[6];
  const float* We2 = (const float*)d_in[7];  const float* be2 = (const float*)d_in[8];
  const float* Wx1 = (const float*)d_in[9];  const float* bx1 = (const float*)d_in[10];
  const float* Wx2 = (const float*)d_in[11]; const float* bx2 = (const float*)d_in[12];
  const float* Wh1 = (const float*)d_in[13]; const float* bh1 = (const float*)d_in[14];
  const float* Wh2 = (const float*)d_in[15]; const float* bh2 = (const float*)d_in[16];

  hipLaunchKernelGGL(egnn_mfma, dim3(NBLK), dim3(256), 0, stream,
                     ped, h_st, h_neigh, rela, mask,
                     We1, be1, We2, be2, Wx1, bx1, Wx2, bx2,
                     Wh1, bh1, Wh2, bh2, (float*)d_out);
}

// Round 9
// 111.875 us; speedup vs baseline: 2.5355x; 1.0500x over previous
//
#include <hip/hip_runtime.h>
#include <hip/hip_bf16.h>

// ConvEGNN3 round 9: round-8 structure (117us) + 3 local fixes:
// 1) scratch re-layout: read-contiguous fragments (lane l does one b128 at
//    s_scr[w][half][l][0]) -> 2 accesses/bank = conflict-free; writes 2-way.
//    stride-36/40 layouts were both ~4-way on reads (6.5M conflict cycles).
//    m_i column-sum keeps conflict-freedom via per-lane rotation of j.
// 2) v_cvt_pk_bf16_f32 (1 op) replaces 3-op add+add+perm pack everywhere.
// 3) m_i partial moved after GEMM3 MFMA issue (overlaps MFMA latency).

typedef __attribute__((ext_vector_type(8))) short short8;
typedef __attribute__((ext_vector_type(4))) float f32x4;
typedef __attribute__((ext_vector_type(2))) float f32x2;
typedef __attribute__((ext_vector_type(2))) unsigned int u32x2;
typedef __attribute__((ext_vector_type(4))) unsigned int u32x4;

#define NODES 16384
#define NPB   16
#define NBLK  (NODES / NPB)

#define MFMA16(a, b, c) __builtin_amdgcn_mfma_f32_16x16x32_bf16((a), (b), (c), 0, 0, 0)

// exact RNE scalar (prologue weight-fragment loads only)
__device__ __forceinline__ unsigned short f2bf(float f) {
  unsigned int u = __float_as_uint(f);
  u += 0x7FFFu + ((u >> 16) & 1u);
  return (unsigned short)(u >> 16);
}
// 1-op pack: dst.lo16 = bf16(lo), dst.hi16 = bf16(hi)  (RNE)
__device__ __forceinline__ unsigned int pk2(float lo, float hi) {
  unsigned int r;
  asm("v_cvt_pk_bf16_f32 %0, %1, %2" : "=v"(r) : "v"(lo), "v"(hi));
  return r;
}
__device__ __forceinline__ float bfl(unsigned int u) { return __uint_as_float(u << 16); }
__device__ __forceinline__ float bfh(unsigned int u) { return __uint_as_float(u & 0xFFFF0000u); }
__device__ __forceinline__ float silu_f(float x) {
  return x * __builtin_amdgcn_rcpf(1.f + __expf(-x));
}
__device__ __forceinline__ f32x4 silu4(f32x4 x) {
  f32x4 r; r[0]=silu_f(x[0]); r[1]=silu_f(x[1]); r[2]=silu_f(x[2]); r[3]=silu_f(x[3]); return r;
}
__device__ __forceinline__ short8 packb(f32x4 a, f32x4 b) {
  u32x4 t;
  t[0] = pk2(a[0], a[1]); t[1] = pk2(a[2], a[3]);
  t[2] = pk2(b[0], b[1]); t[3] = pk2(b[2], b[3]);
  return __builtin_bit_cast(short8, t);
}
__device__ __forceinline__ short8 ldfragT(const float* __restrict__ W, int k0, int col) {
  short8 r;
  #pragma unroll
  for (int m = 0; m < 8; m++) r[m] = (short)f2bf(W[(k0 + m) * 64 + col]);
  return r;
}

__global__ __launch_bounds__(256, 2) void egnn_mfma(
    const float* __restrict__ ped, const float* __restrict__ h_st,
    const float* __restrict__ h_neigh, const float* __restrict__ rela,
    const unsigned char* __restrict__ mask8,
    const float* __restrict__ We1, const float* __restrict__ be1,
    const float* __restrict__ We2, const float* __restrict__ be2,
    const float* __restrict__ Wx1, const float* __restrict__ bx1,
    const float* __restrict__ Wx2, const float* __restrict__ bx2,
    const float* __restrict__ Wh1, const float* __restrict__ bh1,
    const float* __restrict__ Wh2, const float* __restrict__ bh2,
    float* __restrict__ out)
{
  __shared__ __align__(16) float s_hst[16][64];
  __shared__ __align__(16) float s_u[16][64];
  __shared__ __align__(16) float s_miw[4][16][64];
  __shared__ __align__(16) unsigned int s_scr[4][2][64][4];  // per-wave, per-k-half, frag/lane
  __shared__ __align__(16) short8 s_af[16][64];   // c = 8*g + 2*mt + kk; g0=We2, g1=Wx1
  __shared__ float s_cvec[2][64];   // be2, bx1
  __shared__ float s_w1l[64];       // We1 dist row
  __shared__ float s_wx2[64];       // Wx2
  __shared__ float s_aggx[4][16], s_aggy[4][16], s_nn[4][16];
  __shared__ int s_flags[2];

  const int t  = threadIdx.x;
  const int l  = t & 63;
  const int w  = t >> 6;
  const int lg = l >> 4;
  const int jl = l & 15;
  const int base = blockIdx.x * NPB;

  if (t == 0) { s_flags[0] = 1; s_flags[1] = 1; }
  __syncthreads();
  {
    const unsigned int* mw = (const unsigned int*)mask8;
    unsigned int iok = 1, fok = 1;
    #pragma unroll
    for (int q = 0; q < 4; q++) {
      unsigned int v = mw[t * 4 + q];
      if (v > 1u) iok = 0;
      if (v != 0u && v != 0x3F800000u) fok = 0;
    }
    if (!iok) atomicAnd(&s_flags[0], 0);
    if (!fok) atomicAnd(&s_flags[1], 0);
  }
  {
    const f32x4* src = (const f32x4*)(h_st + (size_t)base * 64);
    f32x4* dst = (f32x4*)&s_hst[0][0];
    dst[t] = src[t];
    if (t < 64)        s_cvec[0][t] = be2[t];
    else if (t < 128)  s_cvec[1][t - 64] = bx1[t - 64];
    else if (t < 192)  s_w1l[t - 128] = We1[128 * 64 + (t - 128)];
    else               s_wx2[t - 192] = Wx2[t - 192];
  }
  // stage a2/a3 fragments into LDS: wave w stages combos 4w..4w+3
  #pragma unroll
  for (int ci = 0; ci < 4; ci++) {
    const int c  = 4 * w + ci;
    const int g  = c >> 3, mt = (c >> 1) & 3, kk = c & 1;
    const float* W = g ? Wx1 : We2;
    s_af[c][l] = ldfragT(W, 8 * lg + 32 * kk, 16 * mt + jl);
  }
  __syncthreads();
  const int mode = s_flags[0] ? 0 : (s_flags[1] ? 1 : 2);

  auto ldmask = [&](size_t idx) -> float {
    if (mode == 0)      return (((const int*)mask8)[idx] != 0) ? 1.f : 0.f;
    else if (mode == 1) return (((const float*)mask8)[idx] != 0.f) ? 1.f : 0.f;
    else                return (mask8[idx] != 0) ? 1.f : 0.f;
  };

  // D-quad (ht) of lane (jl,lg) -> scratch fragment slot (write side)
  const int sc_lgp_e = (lg >> 1);      // lgp = (2*ht + lg/2) & 3
  const int sc_m0    = 2 * (lg & 1);   // word pair within fragment

  // ---- U = be1 + h_st @ We1[0:64] ----
  {
    f32x4 uacc = {0.f, 0.f, 0.f, 0.f};
    #pragma unroll
    for (int kk = 0; kk < 2; kk++) {
      short8 au = ldfragT(We1, 8 * lg + 32 * kk, 16 * w + jl);
      f32x4 q0 = *(const f32x4*)&s_hst[jl][8 * lg + 32 * kk];
      f32x4 q1 = *(const f32x4*)&s_hst[jl][8 * lg + 32 * kk + 4];
      uacc = MFMA16(au, packb(q0, q1), uacc);
    }
    f32x4 b1v = *(const f32x4*)(be1 + 16 * w + 4 * lg);
    *(f32x4*)&s_u[jl][16 * w + 4 * lg] = uacc + b1v;
  }

  // ---- a1 (We1 lower) fragments stay in registers/AGPR ----
  short8 a1[4][2];
  #pragma unroll
  for (int mt = 0; mt < 4; mt++)
    #pragma unroll
    for (int kk = 0; kk < 2; kk++)
      a1[mt][kk] = ldfragT(We1 + 64 * 64, 8 * lg + 32 * kk, 16 * mt + jl);
  const float bx2s = bx2[0];

  // ---- initial prefetch (node 0) ----
  const float* hn_lane = h_neigh + ((size_t)base * 64 + 16 * w + jl) * 64 + 8 * lg;
  const size_t ro = (size_t)base * 64 + 16 * w + jl;
  f32x4 pf0 = *(const f32x4*)(hn_lane + 0);
  f32x4 pf1 = *(const f32x4*)(hn_lane + 4);
  f32x4 pf2 = *(const f32x4*)(hn_lane + 32);
  f32x4 pf3 = *(const f32x4*)(hn_lane + 36);
  f32x2 pre = *(const f32x2*)(rela + ro * 6);
  float pmf = ldmask(ro);
  __syncthreads();  // s_u + s_af ready

  // =========================== main loop ===========================
  #pragma unroll 1
  for (int nl = 0; nl < NPB; nl++) {
    // pack FIRST so pf* die before next prefetch issues
    const short8 b1k0 = packb(pf0, pf1);
    const short8 b1k1 = packb(pf2, pf3);
    const f32x2 rr = pre; const float mf = pmf;
    if (nl < NPB - 1) {
      const float* p = hn_lane + (size_t)(nl + 1) * 4096;
      pf0 = *(const f32x4*)(p + 0);  pf1 = *(const f32x4*)(p + 4);
      pf2 = *(const f32x4*)(p + 32); pf3 = *(const f32x4*)(p + 36);
      pre = *(const f32x2*)(rela + (ro + (size_t)(nl + 1) * 64) * 6);
      pmf = ldmask(ro + (size_t)(nl + 1) * 64);
    }
    const float d = sqrtf(rr[0] * rr[0] + rr[1] * rr[1]);

    float msum = mf;
    msum += __shfl_xor(msum, 1, 64); msum += __shfl_xor(msum, 2, 64);
    msum += __shfl_xor(msum, 4, 64); msum += __shfl_xor(msum, 8, 64);
    if (l == 0) s_nn[w][nl] = msum;

    // ---- GEMM1: E^T ----
    f32x4 acc[4];
    #pragma unroll
    for (int ht = 0; ht < 4; ht++) {
      const f32x4 wl = *(const f32x4*)&s_w1l[16 * ht + 4 * lg];
      acc[ht] = *(const f32x4*)&s_u[nl][16 * ht + 4 * lg] + d * wl;
      acc[ht] = MFMA16(a1[ht][0], b1k0, acc[ht]);
      acc[ht] = MFMA16(a1[ht][1], b1k1, acc[ht]);
    }
    #pragma unroll
    for (int ht = 0; ht < 4; ht++) {
      f32x4 e = silu4(acc[ht]);
      u32x2 wv; wv[0] = pk2(e[0], e[1]); wv[1] = pk2(e[2], e[3]);
      const int half = (4 * ht + lg) >> 3;
      const int lgp  = (2 * ht + sc_lgp_e) & 3;
      *(u32x2*)&s_scr[w][half][lgp * 16 + jl][sc_m0] = wv;
    }
    short8 b2k0 = *(const short8*)&s_scr[w][0][l][0];
    short8 b2k1 = *(const short8*)&s_scr[w][1][l][0];

    // ---- GEMM2: M^T (a2 fragments JIT from LDS) ----
    #pragma unroll
    for (int ht = 0; ht < 4; ht++) {
      const short8 f2k0 = s_af[2 * ht][l];
      const short8 f2k1 = s_af[2 * ht + 1][l];
      acc[ht] = *(const f32x4*)&s_cvec[0][16 * ht + 4 * lg];
      acc[ht] = MFMA16(f2k0, b2k0, acc[ht]);
      acc[ht] = MFMA16(f2k1, b2k1, acc[ht]);
    }
    #pragma unroll
    for (int ht = 0; ht < 4; ht++) {
      f32x4 m = silu4(acc[ht]) * mf;
      u32x2 wv; wv[0] = pk2(m[0], m[1]); wv[1] = pk2(m[2], m[3]);
      const int half = (4 * ht + lg) >> 3;
      const int lgp  = (2 * ht + sc_lgp_e) & 3;
      *(u32x2*)&s_scr[w][half][lgp * 16 + jl][sc_m0] = wv;
    }
    short8 b3k0 = *(const short8*)&s_scr[w][0][l][0];
    short8 b3k1 = *(const short8*)&s_scr[w][1][l][0];

    // ---- GEMM3: G^T (a3 fragments JIT from LDS) ----
    #pragma unroll
    for (int ht = 0; ht < 4; ht++) {
      const short8 f3k0 = s_af[8 + 2 * ht][l];
      const short8 f3k1 = s_af[8 + 2 * ht + 1][l];
      acc[ht] = *(const f32x4*)&s_cvec[1][16 * ht + 4 * lg];
      acc[ht] = MFMA16(f3k0, b3k0, acc[ht]);
      acc[ht] = MFMA16(f3k1, b3k1, acc[ht]);
    }

    // ---- m_i partial (reads m from scratch; overlaps GEMM3 MFMA latency) ----
    {
      const int hw = l & 31, jh = l >> 5;
      const int half = hw >> 4;          // h = 2*hw, 2*hw+1
      const int lgp  = (hw & 15) >> 2;
      const int m0   = hw & 3;
      const int rot  = hw >> 2;          // bank-rotation seed
      float pe = 0.f, po = 0.f;
      #pragma unroll
      for (int c = 0; c < 8; c++) {
        const int j = 8 * jh + ((c + rot) & 7);
        unsigned int v = s_scr[w][half][lgp * 16 + j][m0];
        pe += bfl(v); po += bfh(v);
      }
      pe += __shfl_xor(pe, 32, 64);
      po += __shfl_xor(po, 32, 64);
      if (l < 32) {
        f32x2 v2; v2[0] = pe; v2[1] = po;
        *(f32x2*)&s_miw[w][nl][2 * hw] = v2;
      }
    }

    // ---- gate ----
    float gg = 0.f;
    #pragma unroll
    for (int ht = 0; ht < 4; ht++) {
      const f32x4 wx = *(const f32x4*)&s_wx2[16 * ht + 4 * lg];
      f32x4 g = silu4(acc[ht]);
      gg += g[0] * wx[0] + g[1] * wx[1] + g[2] * wx[2] + g[3] * wx[3];
    }
    gg += __shfl_xor(gg, 16, 64);
    gg += __shfl_xor(gg, 32, 64);
    const float gate = gg + bx2s;

    float ax = rr[0] * gate, ay = rr[1] * gate;
    ax += __shfl_xor(ax, 1, 64); ay += __shfl_xor(ay, 1, 64);
    ax += __shfl_xor(ax, 2, 64); ay += __shfl_xor(ay, 2, 64);
    ax += __shfl_xor(ax, 4, 64); ay += __shfl_xor(ay, 4, 64);
    ax += __shfl_xor(ax, 8, 64); ay += __shfl_xor(ay, 8, 64);
    if (l == 0) { s_aggx[w][nl] = ax; s_aggy[w][nl] = ay; }
  }
  __syncthreads();

  // ---- x_new ----
  if (t < 32) {
    const int node = t >> 1, c = t & 1;
    const float nn = s_nn[0][node] + s_nn[1][node] + s_nn[2][node] + s_nn[3][node];
    const float ag = (c ? (s_aggy[0][node] + s_aggy[1][node] + s_aggy[2][node] + s_aggy[3][node])
                        : (s_aggx[0][node] + s_aggx[1][node] + s_aggx[2][node] + s_aggx[3][node]));
    out[(size_t)(base + node) * 2 + c] =
        ped[(size_t)(base + node) * 2 + c] + ag / (nn + 1e-6f);
  }

  // ---- f_h batched over 16 nodes ----
  {
    f32x4 hacc = *(const f32x4*)(bh1 + 16 * w + 4 * lg);
    #pragma unroll
    for (int kk = 0; kk < 4; kk++) {
      short8 ah = ldfragT(Wh1, 8 * lg + 32 * kk, 16 * w + jl);
      f32x4 q0, q1;
      if (kk < 2) {
        q0 = *(const f32x4*)&s_hst[jl][8 * lg + 32 * kk];
        q1 = *(const f32x4*)&s_hst[jl][8 * lg + 32 * kk + 4];
      } else {
        const int off = 8 * lg + 32 * (kk - 2);
        q0 = *(const f32x4*)&s_miw[0][jl][off]     + *(const f32x4*)&s_miw[1][jl][off]
           + *(const f32x4*)&s_miw[2][jl][off]     + *(const f32x4*)&s_miw[3][jl][off];
        q1 = *(const f32x4*)&s_miw[0][jl][off + 4] + *(const f32x4*)&s_miw[1][jl][off + 4]
           + *(const f32x4*)&s_miw[2][jl][off + 4] + *(const f32x4*)&s_miw[3][jl][off + 4];
      }
      hacc = MFMA16(ah, packb(q0, q1), hacc);
    }
    f32x4 h1 = silu4(hacc);
    u32x2 wv; wv[0] = pk2(h1[0], h1[1]); wv[1] = pk2(h1[2], h1[3]);
    const int half = (4 * w + lg) >> 3;          // "ht" = wave id here
    const int lgp  = (2 * w + sc_lgp_e) & 3;
    *(u32x2*)&s_scr[0][half][lgp * 16 + jl][sc_m0] = wv;
  }
  __syncthreads();
  {
    short8 hb0 = *(const short8*)&s_scr[0][0][l][0];
    short8 hb1 = *(const short8*)&s_scr[0][1][l][0];
    short8 aw0 = ldfragT(Wh2, 8 * lg,      16 * w + jl);
    short8 aw1 = ldfragT(Wh2, 8 * lg + 32, 16 * w + jl);
    f32x4 oacc = *(const f32x4*)(bh2 + 16 * w + 4 * lg);
    oacc = MFMA16(aw0, hb0, oacc);
    oacc = MFMA16(aw1, hb1, oacc);
    f32x4 res = oacc + *(const f32x4*)&s_hst[jl][16 * w + 4 * lg];
    *(f32x4*)(out + 32768 + (size_t)(base + jl) * 64 + 16 * w + 4 * lg) = res;
  }
}

extern "C" void kernel_launch(void* const* d_in, const int* in_sizes, int n_in,
                              void* d_out, int out_size, void* d_ws, size_t ws_size,
                              hipStream_t stream) {
  (void)in_sizes; (void)n_in; (void)out_size; (void)d_ws; (void)ws_size;
  const float* ped     = (const float*)d_in[0];
  const float* h_st    = (const float*)d_in[1];
  const float* h_neigh = (const float*)d_in[2];
  const float* rela    = (const float*)d_in[3];
  const unsigned char* mask = (const unsigned char*)d_in[4];
  const float* We1 = (const float*)d_in[5];  const float* be1 = (const float*)d_in[6];
  const float* We2 = (const float*)d_in[7];  const float* be2 = (const float*)d_in[8];
  const float* Wx1 = (const float*)d_in[9];  const float* bx1 = (const float*)d_in[10];
  const float* Wx2 = (const float*)d_in[11]; const float* bx2 = (const float*)d_in[12];
  const float* Wh1 = (const float*)d_in[13]; const float* bh1 = (const float*)d_in[14];
  const float* Wh2 = (const float*)d_in[15]; const float* bh2 = (const float*)d_in[16];

  hipLaunchKernelGGL(egnn_mfma, dim3(NBLK), dim3(256), 0, stream,
                     ped, h_st, h_neigh, rela, mask,
                     We1, be1, We2, be2, Wx1, bx1, Wx2, bx2,
                     Wh1, bh1, Wh2, bh2, (float*)d_out);
}

// Round 10
// 111.341 us; speedup vs baseline: 2.5476x; 1.0048x over previous
//
#include <hip/hip_runtime.h>
#include <hip/hip_bf16.h>

// ConvEGNN3 round 10: round-9 source with ONE change: launch_bounds (256,2)->(256,3).
// r9 measured natural live-V = 72 (cvt_pk cut pack temps; rocprof VGPR_Count 72,
// WRITE_SIZE 4MB = no spill). The (256,3) cap (~84V/86A) that spilled r3/r6
// (live-V ~150 then) is now satisfiable: V 72<=84, A ~48<=86. LDS 51.2KB x3 =
// 153.6 <= 160KB. Expect 3 blocks/CU = 3 waves/SIMD on a latency-bound kernel.

typedef __attribute__((ext_vector_type(8))) short short8;
typedef __attribute__((ext_vector_type(4))) float f32x4;
typedef __attribute__((ext_vector_type(2))) float f32x2;
typedef __attribute__((ext_vector_type(2))) unsigned int u32x2;
typedef __attribute__((ext_vector_type(4))) unsigned int u32x4;

#define NODES 16384
#define NPB   16
#define NBLK  (NODES / NPB)

#define MFMA16(a, b, c) __builtin_amdgcn_mfma_f32_16x16x32_bf16((a), (b), (c), 0, 0, 0)

// exact RNE scalar (prologue weight-fragment loads only)
__device__ __forceinline__ unsigned short f2bf(float f) {
  unsigned int u = __float_as_uint(f);
  u += 0x7FFFu + ((u >> 16) & 1u);
  return (unsigned short)(u >> 16);
}
// 1-op pack: dst.lo16 = bf16(lo), dst.hi16 = bf16(hi)  (RNE)
__device__ __forceinline__ unsigned int pk2(float lo, float hi) {
  unsigned int r;
  asm("v_cvt_pk_bf16_f32 %0, %1, %2" : "=v"(r) : "v"(lo), "v"(hi));
  return r;
}
__device__ __forceinline__ float bfl(unsigned int u) { return __uint_as_float(u << 16); }
__device__ __forceinline__ float bfh(unsigned int u) { return __uint_as_float(u & 0xFFFF0000u); }
__device__ __forceinline__ float silu_f(float x) {
  return x * __builtin_amdgcn_rcpf(1.f + __expf(-x));
}
__device__ __forceinline__ f32x4 silu4(f32x4 x) {
  f32x4 r; r[0]=silu_f(x[0]); r[1]=silu_f(x[1]); r[2]=silu_f(x[2]); r[3]=silu_f(x[3]); return r;
}
__device__ __forceinline__ short8 packb(f32x4 a, f32x4 b) {
  u32x4 t;
  t[0] = pk2(a[0], a[1]); t[1] = pk2(a[2], a[3]);
  t[2] = pk2(b[0], b[1]); t[3] = pk2(b[2], b[3]);
  return __builtin_bit_cast(short8, t);
}
__device__ __forceinline__ short8 ldfragT(const float* __restrict__ W, int k0, int col) {
  short8 r;
  #pragma unroll
  for (int m = 0; m < 8; m++) r[m] = (short)f2bf(W[(k0 + m) * 64 + col]);
  return r;
}

__global__ __launch_bounds__(256, 3) void egnn_mfma(
    const float* __restrict__ ped, const float* __restrict__ h_st,
    const float* __restrict__ h_neigh, const float* __restrict__ rela,
    const unsigned char* __restrict__ mask8,
    const float* __restrict__ We1, const float* __restrict__ be1,
    const float* __restrict__ We2, const float* __restrict__ be2,
    const float* __restrict__ Wx1, const float* __restrict__ bx1,
    const float* __restrict__ Wx2, const float* __restrict__ bx2,
    const float* __restrict__ Wh1, const float* __restrict__ bh1,
    const float* __restrict__ Wh2, const float* __restrict__ bh2,
    float* __restrict__ out)
{
  __shared__ __align__(16) float s_hst[16][64];
  __shared__ __align__(16) float s_u[16][64];
  __shared__ __align__(16) float s_miw[4][16][64];
  __shared__ __align__(16) unsigned int s_scr[4][2][64][4];  // per-wave, per-k-half, frag/lane
  __shared__ __align__(16) short8 s_af[16][64];   // c = 8*g + 2*mt + kk; g0=We2, g1=Wx1
  __shared__ float s_cvec[2][64];   // be2, bx1
  __shared__ float s_w1l[64];       // We1 dist row
  __shared__ float s_wx2[64];       // Wx2
  __shared__ float s_aggx[4][16], s_aggy[4][16], s_nn[4][16];
  __shared__ int s_flags[2];

  const int t  = threadIdx.x;
  const int l  = t & 63;
  const int w  = t >> 6;
  const int lg = l >> 4;
  const int jl = l & 15;
  const int base = blockIdx.x * NPB;

  if (t == 0) { s_flags[0] = 1; s_flags[1] = 1; }
  __syncthreads();
  {
    const unsigned int* mw = (const unsigned int*)mask8;
    unsigned int iok = 1, fok = 1;
    #pragma unroll
    for (int q = 0; q < 4; q++) {
      unsigned int v = mw[t * 4 + q];
      if (v > 1u) iok = 0;
      if (v != 0u && v != 0x3F800000u) fok = 0;
    }
    if (!iok) atomicAnd(&s_flags[0], 0);
    if (!fok) atomicAnd(&s_flags[1], 0);
  }
  {
    const f32x4* src = (const f32x4*)(h_st + (size_t)base * 64);
    f32x4* dst = (f32x4*)&s_hst[0][0];
    dst[t] = src[t];
    if (t < 64)        s_cvec[0][t] = be2[t];
    else if (t < 128)  s_cvec[1][t - 64] = bx1[t - 64];
    else if (t < 192)  s_w1l[t - 128] = We1[128 * 64 + (t - 128)];
    else               s_wx2[t - 192] = Wx2[t - 192];
  }
  // stage a2/a3 fragments into LDS: wave w stages combos 4w..4w+3
  #pragma unroll
  for (int ci = 0; ci < 4; ci++) {
    const int c  = 4 * w + ci;
    const int g  = c >> 3, mt = (c >> 1) & 3, kk = c & 1;
    const float* W = g ? Wx1 : We2;
    s_af[c][l] = ldfragT(W, 8 * lg + 32 * kk, 16 * mt + jl);
  }
  __syncthreads();
  const int mode = s_flags[0] ? 0 : (s_flags[1] ? 1 : 2);

  auto ldmask = [&](size_t idx) -> float {
    if (mode == 0)      return (((const int*)mask8)[idx] != 0) ? 1.f : 0.f;
    else if (mode == 1) return (((const float*)mask8)[idx] != 0.f) ? 1.f : 0.f;
    else                return (mask8[idx] != 0) ? 1.f : 0.f;
  };

  // D-quad (ht) of lane (jl,lg) -> scratch fragment slot (write side)
  const int sc_lgp_e = (lg >> 1);      // lgp = (2*ht + lg/2) & 3
  const int sc_m0    = 2 * (lg & 1);   // word pair within fragment

  // ---- U = be1 + h_st @ We1[0:64] ----
  {
    f32x4 uacc = {0.f, 0.f, 0.f, 0.f};
    #pragma unroll
    for (int kk = 0; kk < 2; kk++) {
      short8 au = ldfragT(We1, 8 * lg + 32 * kk, 16 * w + jl);
      f32x4 q0 = *(const f32x4*)&s_hst[jl][8 * lg + 32 * kk];
      f32x4 q1 = *(const f32x4*)&s_hst[jl][8 * lg + 32 * kk + 4];
      uacc = MFMA16(au, packb(q0, q1), uacc);
    }
    f32x4 b1v = *(const f32x4*)(be1 + 16 * w + 4 * lg);
    *(f32x4*)&s_u[jl][16 * w + 4 * lg] = uacc + b1v;
  }

  // ---- a1 (We1 lower) fragments stay in registers/AGPR ----
  short8 a1[4][2];
  #pragma unroll
  for (int mt = 0; mt < 4; mt++)
    #pragma unroll
    for (int kk = 0; kk < 2; kk++)
      a1[mt][kk] = ldfragT(We1 + 64 * 64, 8 * lg + 32 * kk, 16 * mt + jl);
  const float bx2s = bx2[0];

  // ---- initial prefetch (node 0) ----
  const float* hn_lane = h_neigh + ((size_t)base * 64 + 16 * w + jl) * 64 + 8 * lg;
  const size_t ro = (size_t)base * 64 + 16 * w + jl;
  f32x4 pf0 = *(const f32x4*)(hn_lane + 0);
  f32x4 pf1 = *(const f32x4*)(hn_lane + 4);
  f32x4 pf2 = *(const f32x4*)(hn_lane + 32);
  f32x4 pf3 = *(const f32x4*)(hn_lane + 36);
  f32x2 pre = *(const f32x2*)(rela + ro * 6);
  float pmf = ldmask(ro);
  __syncthreads();  // s_u + s_af ready

  // =========================== main loop ===========================
  #pragma unroll 1
  for (int nl = 0; nl < NPB; nl++) {
    // pack FIRST so pf* die before next prefetch issues
    const short8 b1k0 = packb(pf0, pf1);
    const short8 b1k1 = packb(pf2, pf3);
    const f32x2 rr = pre; const float mf = pmf;
    if (nl < NPB - 1) {
      const float* p = hn_lane + (size_t)(nl + 1) * 4096;
      pf0 = *(const f32x4*)(p + 0);  pf1 = *(const f32x4*)(p + 4);
      pf2 = *(const f32x4*)(p + 32); pf3 = *(const f32x4*)(p + 36);
      pre = *(const f32x2*)(rela + (ro + (size_t)(nl + 1) * 64) * 6);
      pmf = ldmask(ro + (size_t)(nl + 1) * 64);
    }
    const float d = sqrtf(rr[0] * rr[0] + rr[1] * rr[1]);

    float msum = mf;
    msum += __shfl_xor(msum, 1, 64); msum += __shfl_xor(msum, 2, 64);
    msum += __shfl_xor(msum, 4, 64); msum += __shfl_xor(msum, 8, 64);
    if (l == 0) s_nn[w][nl] = msum;

    // ---- GEMM1: E^T ----
    f32x4 acc[4];
    #pragma unroll
    for (int ht = 0; ht < 4; ht++) {
      const f32x4 wl = *(const f32x4*)&s_w1l[16 * ht + 4 * lg];
      acc[ht] = *(const f32x4*)&s_u[nl][16 * ht + 4 * lg] + d * wl;
      acc[ht] = MFMA16(a1[ht][0], b1k0, acc[ht]);
      acc[ht] = MFMA16(a1[ht][1], b1k1, acc[ht]);
    }
    #pragma unroll
    for (int ht = 0; ht < 4; ht++) {
      f32x4 e = silu4(acc[ht]);
      u32x2 wv; wv[0] = pk2(e[0], e[1]); wv[1] = pk2(e[2], e[3]);
      const int half = (4 * ht + lg) >> 3;
      const int lgp  = (2 * ht + sc_lgp_e) & 3;
      *(u32x2*)&s_scr[w][half][lgp * 16 + jl][sc_m0] = wv;
    }
    short8 b2k0 = *(const short8*)&s_scr[w][0][l][0];
    short8 b2k1 = *(const short8*)&s_scr[w][1][l][0];

    // ---- GEMM2: M^T (a2 fragments JIT from LDS) ----
    #pragma unroll
    for (int ht = 0; ht < 4; ht++) {
      const short8 f2k0 = s_af[2 * ht][l];
      const short8 f2k1 = s_af[2 * ht + 1][l];
      acc[ht] = *(const f32x4*)&s_cvec[0][16 * ht + 4 * lg];
      acc[ht] = MFMA16(f2k0, b2k0, acc[ht]);
      acc[ht] = MFMA16(f2k1, b2k1, acc[ht]);
    }
    #pragma unroll
    for (int ht = 0; ht < 4; ht++) {
      f32x4 m = silu4(acc[ht]) * mf;
      u32x2 wv; wv[0] = pk2(m[0], m[1]); wv[1] = pk2(m[2], m[3]);
      const int half = (4 * ht + lg) >> 3;
      const int lgp  = (2 * ht + sc_lgp_e) & 3;
      *(u32x2*)&s_scr[w][half][lgp * 16 + jl][sc_m0] = wv;
    }
    short8 b3k0 = *(const short8*)&s_scr[w][0][l][0];
    short8 b3k1 = *(const short8*)&s_scr[w][1][l][0];

    // ---- GEMM3: G^T (a3 fragments JIT from LDS) ----
    #pragma unroll
    for (int ht = 0; ht < 4; ht++) {
      const short8 f3k0 = s_af[8 + 2 * ht][l];
      const short8 f3k1 = s_af[8 + 2 * ht + 1][l];
      acc[ht] = *(const f32x4*)&s_cvec[1][16 * ht + 4 * lg];
      acc[ht] = MFMA16(f3k0, b3k0, acc[ht]);
      acc[ht] = MFMA16(f3k1, b3k1, acc[ht]);
    }

    // ---- m_i partial (reads m from scratch; overlaps GEMM3 MFMA latency) ----
    {
      const int hw = l & 31, jh = l >> 5;
      const int half = hw >> 4;          // h = 2*hw, 2*hw+1
      const int lgp  = (hw & 15) >> 2;
      const int m0   = hw & 3;
      const int rot  = hw >> 2;          // bank-rotation seed
      float pe = 0.f, po = 0.f;
      #pragma unroll
      for (int c = 0; c < 8; c++) {
        const int j = 8 * jh + ((c + rot) & 7);
        unsigned int v = s_scr[w][half][lgp * 16 + j][m0];
        pe += bfl(v); po += bfh(v);
      }
      pe += __shfl_xor(pe, 32, 64);
      po += __shfl_xor(po, 32, 64);
      if (l < 32) {
        f32x2 v2; v2[0] = pe; v2[1] = po;
        *(f32x2*)&s_miw[w][nl][2 * hw] = v2;
      }
    }

    // ---- gate ----
    float gg = 0.f;
    #pragma unroll
    for (int ht = 0; ht < 4; ht++) {
      const f32x4 wx = *(const f32x4*)&s_wx2[16 * ht + 4 * lg];
      f32x4 g = silu4(acc[ht]);
      gg += g[0] * wx[0] + g[1] * wx[1] + g[2] * wx[2] + g[3] * wx[3];
    }
    gg += __shfl_xor(gg, 16, 64);
    gg += __shfl_xor(gg, 32, 64);
    const float gate = gg + bx2s;

    float ax = rr[0] * gate, ay = rr[1] * gate;
    ax += __shfl_xor(ax, 1, 64); ay += __shfl_xor(ay, 1, 64);
    ax += __shfl_xor(ax, 2, 64); ay += __shfl_xor(ay, 2, 64);
    ax += __shfl_xor(ax, 4, 64); ay += __shfl_xor(ay, 4, 64);
    ax += __shfl_xor(ax, 8, 64); ay += __shfl_xor(ay, 8, 64);
    if (l == 0) { s_aggx[w][nl] = ax; s_aggy[w][nl] = ay; }
  }
  __syncthreads();

  // ---- x_new ----
  if (t < 32) {
    const int node = t >> 1, c = t & 1;
    const float nn = s_nn[0][node] + s_nn[1][node] + s_nn[2][node] + s_nn[3][node];
    const float ag = (c ? (s_aggy[0][node] + s_aggy[1][node] + s_aggy[2][node] + s_aggy[3][node])
                        : (s_aggx[0][node] + s_aggx[1][node] + s_aggx[2][node] + s_aggx[3][node]));
    out[(size_t)(base + node) * 2 + c] =
        ped[(size_t)(base + node) * 2 + c] + ag / (nn + 1e-6f);
  }

  // ---- f_h batched over 16 nodes ----
  {
    f32x4 hacc = *(const f32x4*)(bh1 + 16 * w + 4 * lg);
    #pragma unroll
    for (int kk = 0; kk < 4; kk++) {
      short8 ah = ldfragT(Wh1, 8 * lg + 32 * kk, 16 * w + jl);
      f32x4 q0, q1;
      if (kk < 2) {
        q0 = *(const f32x4*)&s_hst[jl][8 * lg + 32 * kk];
        q1 = *(const f32x4*)&s_hst[jl][8 * lg + 32 * kk + 4];
      } else {
        const int off = 8 * lg + 32 * (kk - 2);
        q0 = *(const f32x4*)&s_miw[0][jl][off]     + *(const f32x4*)&s_miw[1][jl][off]
           + *(const f32x4*)&s_miw[2][jl][off]     + *(const f32x4*)&s_miw[3][jl][off];
        q1 = *(const f32x4*)&s_miw[0][jl][off + 4] + *(const f32x4*)&s_miw[1][jl][off + 4]
           + *(const f32x4*)&s_miw[2][jl][off + 4] + *(const f32x4*)&s_miw[3][jl][off + 4];
      }
      hacc = MFMA16(ah, packb(q0, q1), hacc);
    }
    f32x4 h1 = silu4(hacc);
    u32x2 wv; wv[0] = pk2(h1[0], h1[1]); wv[1] = pk2(h1[2], h1[3]);
    const int half = (4 * w + lg) >> 3;          // "ht" = wave id here
    const int lgp  = (2 * w + sc_lgp_e) & 3;
    *(u32x2*)&s_scr[0][half][lgp * 16 + jl][sc_m0] = wv;
  }
  __syncthreads();
  {
    short8 hb0 = *(const short8*)&s_scr[0][0][l][0];
    short8 hb1 = *(const short8*)&s_scr[0][1][l][0];
    short8 aw0 = ldfragT(Wh2, 8 * lg,      16 * w + jl);
    short8 aw1 = ldfragT(Wh2, 8 * lg + 32, 16 * w + jl);
    f32x4 oacc = *(const f32x4*)(bh2 + 16 * w + 4 * lg);
    oacc = MFMA16(aw0, hb0, oacc);
    oacc = MFMA16(aw1, hb1, oacc);
    f32x4 res = oacc + *(const f32x4*)&s_hst[jl][16 * w + 4 * lg];
    *(f32x4*)(out + 32768 + (size_t)(base + jl) * 64 + 16 * w + 4 * lg) = res;
  }
}

extern "C" void kernel_launch(void* const* d_in, const int* in_sizes, int n_in,
                              void* d_out, int out_size, void* d_ws, size_t ws_size,
                              hipStream_t stream) {
  (void)in_sizes; (void)n_in; (void)out_size; (void)d_ws; (void)ws_size;
  const float* ped     = (const float*)d_in[0];
  const float* h_st    = (const float*)d_in[1];
  const float* h_neigh = (const float*)d_in[2];
  const float* rela    = (const float*)d_in[3];
  const unsigned char* mask = (const unsigned char*)d_in[4];
  const float* We1 = (const float*)d_in[5];  const float* be1 = (const float*)d_in[6];
  const float* We2 = (const float*)d_in[7];  const float* be2 = (const float*)d_in[8];
  const float* Wx1 = (const float*)d_in[9];  const float* bx1 = (const float*)d_in[10];
  const float* Wx2 = (const float*)d_in[11]; const float* bx2 = (const float*)d_in[12];
  const float* Wh1 = (const float*)d_in[13]; const float* bh1 = (const float*)d_in[14];
  const float* Wh2 = (const float*)d_in[15]; const float* bh2 = (const float*)d_in[16];

  hipLaunchKernelGGL(egnn_mfma, dim3(NBLK), dim3(256), 0, stream,
                     ped, h_st, h_neigh, rela, mask,
                     We1, be1, We2, be2, Wx1, bx1, Wx2, bx2,
                     Wh1, bh1, Wh2, bh2, (float*)d_out);
}